// Round 1
// 507.574 us; speedup vs baseline: 1.0935x; 1.0935x over previous
//
#include <hip/hip_runtime.h>

typedef unsigned short ushort_t;
typedef __attribute__((ext_vector_type(8))) short short8;
typedef __attribute__((ext_vector_type(4))) float f32x4;

#define B_ 2
#define HW_ 65536          // 256*256 per batch
#define MTOT_ 131072       // B*H*W rows
#define C_ 192
#define C3_ 576
#define HEADS_ 4
#define CH_ 48

// ---- workspace layout (bytes), total ~302.5 MB ----
#define OFF_QKV0  ((size_t)0)                       // bf16 131072*576*2 = 150,994,944
#define OFF_QKV1  ((size_t)150994944)               // bf16, same size
#define OFF_XB    OFF_QKV1                          // bf16 x (50.3 MB) aliases qkv1: dead before dwconv writes
#define OFF_BT    ((size_t)301989888)               // w_qkv^T bf16 576*192*2 = 221,184
#define OFF_S     ((size_t)302211072)               // fp32 8*48*48 = 73,728 B
#define OFF_NQ    ((size_t)302284800)               // fp32 8*48 = 1,536 B
#define OFF_NK    ((size_t)302286336)               // fp32 8*48 = 1,536 B
#define OFF_ATTN  ((size_t)302287872)               // fp32 8*48*48 = 73,728 B
#define OFF_MT    ((size_t)302361600)               // bf16 2*192*192 = 147,456 B

__device__ __forceinline__ float b2f(ushort_t u) {
    unsigned v = ((unsigned)u) << 16;
    return __builtin_bit_cast(float, v);
}
__device__ __forceinline__ ushort_t f2b(float f) {
    unsigned u = __builtin_bit_cast(unsigned, f);
    u = (u + 0x7fffu + ((u >> 16) & 1u)) >> 16;   // RNE
    return (ushort_t)u;
}
__device__ __forceinline__ void storev(float* p, float v) { *p = v; }
__device__ __forceinline__ void storev(ushort_t* p, float v) { *p = f2b(v); }

// convert x fp32 -> bf16 (8 elems/thread)
__global__ void k_cvt_x(const float* __restrict__ x, ushort_t* __restrict__ xb) {
    int i = (blockIdx.x * 256 + threadIdx.x) * 8;   // 12288*256*8 = 25,165,824 exactly
    float4 a = *(const float4*)(x + i);
    float4 b = *(const float4*)(x + i + 4);
    ushort_t o[8];
    o[0] = f2b(a.x); o[1] = f2b(a.y); o[2] = f2b(a.z); o[3] = f2b(a.w);
    o[4] = f2b(b.x); o[5] = f2b(b.y); o[6] = f2b(b.z); o[7] = f2b(b.w);
    *(uint4*)(xb + i) = *(uint4*)o;
}

// K0: transpose+convert w_qkv fp32 [192,576] -> bf16 [576,192]
__global__ void k0_transpose(const float* __restrict__ w, ushort_t* __restrict__ bt) {
    int idx = blockIdx.x * 256 + threadIdx.x;        // 576*192 = 110592 exactly
    int n = idx / 192, k = idx - n * 192;
    bt[idx] = f2b(w[k * 576 + n]);
}

// MFMA GEMM: C[M,N] = A[M,192](bf16) * BT[N,192]^T(bf16) + bias(fp32).  64x64 tile,
// BK=64, 4 waves each 32x32 (2x2 of 16x16x32 bf16 mfma). bstride!=0 selects a
// per-batch B matrix by row/65536 (the fused attn*Wout matrix).
// NOTE: n-tile on blockIdx.x, m-tile on blockIdx.y so consecutive blocks share
// the same A-tile (L1/L2-hot) instead of streaming A once per n-tile.
template <typename OutT>
__global__ __launch_bounds__(256) void gemm_k192(
    const ushort_t* __restrict__ A, int lda, int acol0,
    const ushort_t* __restrict__ BT, int bstride,
    const float* __restrict__ bias,
    OutT* __restrict__ Cout, int ldc)
{
    const int m0 = blockIdx.y * 64;
    const int n0 = blockIdx.x * 64;
    const ushort_t* bt = BT + (bstride ? (size_t)(m0 >> 16) * (size_t)bstride : 0);

    __shared__ ushort_t As[64 * 72];   // stride 72 elems: 16B-aligned rows
    __shared__ ushort_t Bs[64 * 72];

    const int t = threadIdx.x;
    const int wave = t >> 6, lane = t & 63;
    const int quad = lane >> 4, l15 = lane & 15;
    const int wm = (wave >> 1) * 32, wn = (wave & 1) * 32;
    const int srow = t >> 2, scol = (t & 3) * 16;

    f32x4 acc[2][2] = {};

    for (int kk = 0; kk < 192; kk += 64) {
        const ushort_t* ga = A + (size_t)(m0 + srow) * lda + acol0 + kk + scol;
        uint4 va0 = *(const uint4*)ga;
        uint4 va1 = *(const uint4*)(ga + 8);
        const ushort_t* gb = bt + (size_t)(n0 + srow) * 192 + kk + scol;
        uint4 vb0 = *(const uint4*)gb;
        uint4 vb1 = *(const uint4*)(gb + 8);
        *(uint4*)&As[srow * 72 + scol] = va0;
        *(uint4*)&As[srow * 72 + scol + 8] = va1;
        *(uint4*)&Bs[srow * 72 + scol] = vb0;
        *(uint4*)&Bs[srow * 72 + scol + 8] = vb1;
        __syncthreads();
#pragma unroll
        for (int ks = 0; ks < 2; ks++) {
            short8 a0 = *(const short8*)&As[(wm + l15) * 72 + ks * 32 + quad * 8];
            short8 a1 = *(const short8*)&As[(wm + 16 + l15) * 72 + ks * 32 + quad * 8];
            short8 b0 = *(const short8*)&Bs[(wn + l15) * 72 + ks * 32 + quad * 8];
            short8 b1 = *(const short8*)&Bs[(wn + 16 + l15) * 72 + ks * 32 + quad * 8];
            acc[0][0] = __builtin_amdgcn_mfma_f32_16x16x32_bf16(a0, b0, acc[0][0], 0, 0, 0);
            acc[0][1] = __builtin_amdgcn_mfma_f32_16x16x32_bf16(a0, b1, acc[0][1], 0, 0, 0);
            acc[1][0] = __builtin_amdgcn_mfma_f32_16x16x32_bf16(a1, b0, acc[1][0], 0, 0, 0);
            acc[1][1] = __builtin_amdgcn_mfma_f32_16x16x32_bf16(a1, b1, acc[1][1], 0, 0, 0);
        }
        __syncthreads();
    }
#pragma unroll
    for (int sm = 0; sm < 2; sm++) {
#pragma unroll
        for (int sn = 0; sn < 2; sn++) {
            int col = n0 + wn + sn * 16 + l15;
            float bv = bias ? bias[col] : 0.f;
#pragma unroll
            for (int r = 0; r < 4; r++) {
                int row = m0 + wm + sm * 16 + quad * 4 + r;
                storev(&Cout[(size_t)row * ldc + col], acc[sm][sn][r] + bv);
            }
        }
    }
}

// K2: 3x3 depthwise conv, SAME zero-pad, fp32 weights/bias, bf16 act in/out.
// Register-sliding formulation: each thread owns (b, x, c8) and a strip of
// R_STRIP=16 output rows. Each input row is loaded ONCE (3 x-taps, 16B each)
// and contributed to the up-to-3 output rows that consume it via 3 rotating
// 8-channel accumulators. Loads/output drop from 9 to ~3.4; unpack happens
// once per loaded element. All rotation indices and strip-range conditions
// are compile-time constants after full unroll (roles depend only on RR).
#define R_STRIP 16

__global__ __launch_bounds__(256) void k2_dwconv(const ushort_t* __restrict__ qkv0,
        const float* __restrict__ wdw, const float* __restrict__ bdw,
        ushort_t* __restrict__ qkv1)
{
    const int tid = blockIdx.x * 256 + threadIdx.x;   // 2*16*256*72 = 589,824 exactly
    const int c8 = tid % 72;
    const int t1 = tid / 72;                 // = (b*16 + s)*256 + x
    const int x  = t1 & 255;
    const int t2 = t1 >> 8;
    const int s  = t2 & 15;
    const int b  = t2 >> 4;
    const int y0 = s * R_STRIP;
    const int cbase = c8 * 8;

    const bool xm = (x > 0), xp = (x < 255);
    const ushort_t* colbase = qkv0 + ((size_t)(b * HW_ + x) * C3_ + cbase);
    ushort_t*       ocol    = qkv1 + ((size_t)(b * HW_ + x) * C3_ + cbase);
    const size_t rstride = (size_t)256 * C3_;         // elems per image row

    // preload weights [ky][kx][8] and bias (L1/L2-hot, loaded once per thread)
    float w[3][3][8], bw[8];
#pragma unroll
    for (int ky = 0; ky < 3; ++ky)
#pragma unroll
        for (int kx = 0; kx < 3; ++kx) {
            const float* wp = wdw + ((ky * 3 + kx) * C3_ + cbase);
            float4 lo = *(const float4*)wp;
            float4 hi = *(const float4*)(wp + 4);
            w[ky][kx][0] = lo.x; w[ky][kx][1] = lo.y; w[ky][kx][2] = lo.z; w[ky][kx][3] = lo.w;
            w[ky][kx][4] = hi.x; w[ky][kx][5] = hi.y; w[ky][kx][6] = hi.z; w[ky][kx][7] = hi.w;
        }
    {
        float4 lo = *(const float4*)(bdw + cbase);
        float4 hi = *(const float4*)(bdw + cbase + 4);
        bw[0] = lo.x; bw[1] = lo.y; bw[2] = lo.z; bw[3] = lo.w;
        bw[4] = hi.x; bw[5] = hi.y; bw[6] = hi.z; bw[7] = hi.w;
    }

    const uint4 z4 = make_uint4(0, 0, 0, 0);
    auto loadrow = [&](int r, uint4& d0, uint4& d1, uint4& d2) {
        if ((unsigned)r <= 255u) {
            const ushort_t* p = colbase + (size_t)r * rstride;
            d1 = *(const uint4*)p;
            d0 = xm ? *(const uint4*)(p - C3_) : z4;
            d2 = xp ? *(const uint4*)(p + C3_) : z4;
        } else { d0 = z4; d1 = z4; d2 = z4; }
    };

    // acc role: output row o uses A[(o - y0 + 1) % 3]; at step RR (input row
    // r = y0-1+RR): prev-out(r-1) -> (RR+2)%3, cur-out(r) -> RR%3,
    // next-out(r+1) -> (RR+1)%3 — all compile-time after unroll.
    float A[3][8] = {};
    uint4 c0, c1, c2;
    loadrow(y0 - 1, c0, c1, c2);

#pragma unroll
    for (int RR = 0; RR < R_STRIP + 2; ++RR) {
        const int r = y0 - 1 + RR;
        uint4 n0 = z4, n1 = z4, n2 = z4;
        if (RR < R_STRIP + 1) loadrow(r + 1, n0, n1, n2);   // 1-step prefetch

        float rf[3][8];
        {
            const ushort_t* dd = (const ushort_t*)&c0;
#pragma unroll
            for (int j = 0; j < 8; ++j) rf[0][j] = b2f(dd[j]);
            dd = (const ushort_t*)&c1;
#pragma unroll
            for (int j = 0; j < 8; ++j) rf[1][j] = b2f(dd[j]);
            dd = (const ushort_t*)&c2;
#pragma unroll
            for (int j = 0; j < 8; ++j) rf[2][j] = b2f(dd[j]);
        }

        if (RR >= 1 && RR <= R_STRIP) {           // row r -> out r (ky=0)
#pragma unroll
            for (int kx = 0; kx < 3; ++kx)
#pragma unroll
                for (int j = 0; j < 8; ++j)
                    A[RR % 3][j] = fmaf(rf[kx][j], w[1][kx][j], A[RR % 3][j]);
        }
        if (RR <= R_STRIP - 1) {                  // row r -> out r+1 (ky=-1)
#pragma unroll
            for (int kx = 0; kx < 3; ++kx)
#pragma unroll
                for (int j = 0; j < 8; ++j)
                    A[(RR + 1) % 3][j] = fmaf(rf[kx][j], w[0][kx][j], A[(RR + 1) % 3][j]);
        }
        if (RR >= 2) {                            // row r -> out r-1 (ky=+1), then out r-1 done
#pragma unroll
            for (int kx = 0; kx < 3; ++kx)
#pragma unroll
                for (int j = 0; j < 8; ++j)
                    A[(RR + 2) % 3][j] = fmaf(rf[kx][j], w[2][kx][j], A[(RR + 2) % 3][j]);
            ushort_t ov[8];
#pragma unroll
            for (int j = 0; j < 8; ++j) {
                ov[j] = f2b(A[(RR + 2) % 3][j] + bw[j]);
                A[(RR + 2) % 3][j] = 0.f;
            }
            *(uint4*)(ocol + (size_t)(r - 1) * rstride) = *(uint4*)ov;
        }
        c0 = n0; c1 = n1; c2 = n2;
    }
}

// K3: per (b,head) Gram matrix S[48,48] = sum_n q[n,cq]*k[n,ck], plus sum(q^2), sum(k^2)
// fused into the same LDS-staged pass. Partial sums -> global atomics.
__global__ __launch_bounds__(256) void k3_gram(const ushort_t* __restrict__ qkv1,
        float* __restrict__ S, float* __restrict__ NQ, float* __restrict__ NK)
{
    int bh = blockIdx.y;              // 0..7
    int b = bh >> 2, h = bh & 3;
    int n0 = blockIdx.x * 512;        // 128 slices of 512 rows
    __shared__ float Lq[32][49];
    __shared__ float Lk[32][49];
    int t = threadIdx.x;
    int cq0 = (t >> 4) * 3, ck0 = (t & 15) * 3;
    float acc[3][3] = {};
    float nacc = 0.f;

    for (int c0 = 0; c0 < 512; c0 += 32) {
        for (int i = t; i < 384; i += 256) {
            int row = i / 12, s = i - row * 12;
            int ch = (s < 6) ? (h * CH_ + s * 8) : (C_ + h * CH_ + (s - 6) * 8);
            uint4 d = *(const uint4*)(qkv1 + ((size_t)(b * HW_ + n0 + c0 + row)) * C3_ + ch);
            const ushort_t* dd = (const ushort_t*)&d;
            float* dst = (s < 6) ? &Lq[row][s * 8] : &Lk[row][(s - 6) * 8];
#pragma unroll
            for (int j = 0; j < 8; j++) dst[j] = b2f(dd[j]);
        }
        __syncthreads();
#pragma unroll 4
        for (int n = 0; n < 32; n++) {
            float q0 = Lq[n][cq0], q1 = Lq[n][cq0 + 1], q2 = Lq[n][cq0 + 2];
            float k0 = Lk[n][ck0], k1 = Lk[n][ck0 + 1], k2 = Lk[n][ck0 + 2];
            acc[0][0] += q0 * k0; acc[0][1] += q0 * k1; acc[0][2] += q0 * k2;
            acc[1][0] += q1 * k0; acc[1][1] += q1 * k1; acc[1][2] += q1 * k2;
            acc[2][0] += q2 * k0; acc[2][1] += q2 * k1; acc[2][2] += q2 * k2;
            if (t < 96) { float v = (t < 48) ? Lq[n][t] : Lk[n][t - 48]; nacc += v * v; }
        }
        __syncthreads();
    }
    float* Sp = S + bh * 2304;
#pragma unroll
    for (int i = 0; i < 3; i++)
#pragma unroll
        for (int j = 0; j < 3; j++)
            atomicAdd(&Sp[(cq0 + i) * 48 + ck0 + j], acc[i][j]);
    if (t < 48) atomicAdd(&NQ[bh * 48 + t], nacc);
    else if (t < 96) atomicAdd(&NK[bh * 48 + t - 48], nacc);
}

// K4a: attn = softmax_row( S * temp / (|q||k|) ), one 64-thread block per (bh,cq) row
__global__ void k4a_softmax(const float* __restrict__ S, const float* __restrict__ NQ,
                            const float* __restrict__ NK, const float* __restrict__ temp,
                            float* __restrict__ ATT)
{
    int bh = blockIdx.y, cq = blockIdx.x;
    int h = bh & 3;
    int t = threadIdx.x;
    float nq = fmaxf(sqrtf(NQ[bh * 48 + cq]), 1e-12f);
    float tv = temp[h];
    float logit = -1e30f;
    if (t < 48) {
        float nk = fmaxf(sqrtf(NK[bh * 48 + t]), 1e-12f);
        logit = S[bh * 2304 + cq * 48 + t] * tv / (nq * nk);
    }
    float m = logit;
    for (int o = 32; o > 0; o >>= 1) m = fmaxf(m, __shfl_xor(m, o));
    float e = (t < 48) ? __expf(logit - m) : 0.f;
    float ssum = e;
    for (int o = 32; o > 0; o >>= 1) ssum += __shfl_xor(ssum, o);
    if (t < 48) ATT[bh * 2304 + cq * 48 + t] = e / ssum;
}

// K4b: fuse attention-apply + output projection into one per-batch 192x192 matrix,
// stored TRANSPOSED (MT[b][j][D] = sum_cq attn[b,h(D),cq,D%48] * Wout[h(D)*48+cq, j])
// so the final GEMM's B-operand reads contiguous K.
__global__ void k4b_buildM(const float* __restrict__ ATT, const float* __restrict__ wout,
                           ushort_t* __restrict__ MT)
{
    int idx = blockIdx.x * 256 + threadIdx.x;      // 2*192*192 = 73728 exactly
    int b = idx / 36864; int rem = idx - b * 36864;
    int j = rem / 192;   int d = rem - j * 192;
    int h = d / 48, dd = d - h * 48;
    const float* ap = ATT + (size_t)(b * 4 + h) * 2304 + dd;   // stride 48 over cq
    const float* wp = wout + (size_t)(h * 48) * 192 + j;       // stride 192 over cq
    float s = 0.f;
#pragma unroll 8
    for (int cq = 0; cq < 48; cq++) s += ap[cq * 48] * wp[cq * 192];
    MT[idx] = f2b(s);
}

extern "C" void kernel_launch(void* const* d_in, const int* in_sizes, int n_in,
                              void* d_out, int out_size, void* d_ws, size_t ws_size,
                              hipStream_t stream) {
    const float* x     = (const float*)d_in[0];
    const float* w_qkv = (const float*)d_in[1];
    const float* b_qkv = (const float*)d_in[2];
    const float* w_dw  = (const float*)d_in[3];
    const float* b_dw  = (const float*)d_in[4];
    const float* temp  = (const float*)d_in[5];
    const float* w_out = (const float*)d_in[6];
    const float* b_out = (const float*)d_in[7];
    float* out = (float*)d_out;

    char* ws = (char*)d_ws;
    ushort_t* qkv0 = (ushort_t*)(ws + OFF_QKV0);
    ushort_t* qkv1 = (ushort_t*)(ws + OFF_QKV1);
    ushort_t* xb   = (ushort_t*)(ws + OFF_XB);
    ushort_t* btq  = (ushort_t*)(ws + OFF_BT);
    float*    Sb   = (float*)(ws + OFF_S);
    float*    NQ   = (float*)(ws + OFF_NQ);
    float*    NK   = (float*)(ws + OFF_NK);
    float*    ATT  = (float*)(ws + OFF_ATTN);
    ushort_t* MT   = (ushort_t*)(ws + OFF_MT);

    // zero the atomic accumulators (S + NQ + NK are contiguous: 76,800 B)
    hipMemsetAsync(ws + OFF_S, 0, 76800, stream);

    k_cvt_x<<<12288, 256, 0, stream>>>(x, xb);
    k0_transpose<<<432, 256, 0, stream>>>(w_qkv, btq);
    // qkv0 = x @ w_qkv + b_qkv   (bf16 out); n-tiles on grid.x so A-tiles stay hot
    gemm_k192<ushort_t><<<dim3(9, 2048), 256, 0, stream>>>(xb, 192, 0, btq, 0, b_qkv, qkv0, 576);
    // qkv1 = depthwise3x3(qkv0) + b_dw   (clobbers xb — xb is dead here)
    k2_dwconv<<<2304, 256, 0, stream>>>(qkv0, w_dw, b_dw, qkv1);
    // Gram matrices + squared norms
    k3_gram<<<dim3(128, 8), 256, 0, stream>>>(qkv1, Sb, NQ, NK);
    // softmax(normalized, temperature-scaled)
    k4a_softmax<<<dim3(48, 8), 64, 0, stream>>>(Sb, NQ, NK, temp, ATT);
    // fused (blockdiag attn)^T @ Wout, transposed for the GEMM
    k4b_buildM<<<288, 256, 0, stream>>>(ATT, w_out, MT);
    // out = v @ M_b + b_out   (fp32 out)
    gemm_k192<float><<<dim3(3, 2048), 256, 0, stream>>>(qkv1, 576, 384, MT, 36864, b_out, out, 192);
}

// Round 2
// 449.144 us; speedup vs baseline: 1.2358x; 1.1301x over previous
//
#include <hip/hip_runtime.h>

typedef unsigned short ushort_t;
typedef __attribute__((ext_vector_type(8))) short short8;
typedef __attribute__((ext_vector_type(4))) float f32x4;

#define B_ 2
#define HW_ 65536          // 256*256 per batch
#define MTOT_ 131072       // B*H*W rows
#define C_ 192
#define C3_ 576
#define HEADS_ 4
#define CH_ 48

// ---- workspace layout (bytes), total ~302.5 MB ----
#define OFF_QKV0  ((size_t)0)                       // bf16 131072*576*2 = 150,994,944
#define OFF_QKV1  ((size_t)150994944)               // bf16, same size
#define OFF_XB    OFF_QKV1                          // bf16 x (50.3 MB) aliases qkv1: dead before dwconv writes
#define OFF_P     OFF_QKV0                          // gram partials (15.7 MB) alias qkv0: dead after dwconv
#define OFF_BT    ((size_t)301989888)               // w_qkv^T bf16 576*192*2 = 221,184
#define OFF_S     ((size_t)302211072)               // fp32 8*48*48 = 73,728 B
#define OFF_NQ    ((size_t)302284800)               // fp32 8*48 = 1,536 B
#define OFF_NK    ((size_t)302286336)               // fp32 8*48 = 1,536 B
#define OFF_ATTN  ((size_t)302287872)               // fp32 8*48*48 = 73,728 B
#define OFF_MT    ((size_t)302361600)               // bf16 2*192*192 = 147,456 B

__device__ __forceinline__ float b2f(ushort_t u) {
    unsigned v = ((unsigned)u) << 16;
    return __builtin_bit_cast(float, v);
}
__device__ __forceinline__ ushort_t f2b(float f) {
    unsigned u = __builtin_bit_cast(unsigned, f);
    u = (u + 0x7fffu + ((u >> 16) & 1u)) >> 16;   // RNE
    return (ushort_t)u;
}
__device__ __forceinline__ void storev(float* p, float v) { *p = v; }
__device__ __forceinline__ void storev(ushort_t* p, float v) { *p = f2b(v); }

// convert x fp32 -> bf16 (8 elems/thread)
__global__ void k_cvt_x(const float* __restrict__ x, ushort_t* __restrict__ xb) {
    int i = (blockIdx.x * 256 + threadIdx.x) * 8;   // 12288*256*8 = 25,165,824 exactly
    float4 a = *(const float4*)(x + i);
    float4 b = *(const float4*)(x + i + 4);
    ushort_t o[8];
    o[0] = f2b(a.x); o[1] = f2b(a.y); o[2] = f2b(a.z); o[3] = f2b(a.w);
    o[4] = f2b(b.x); o[5] = f2b(b.y); o[6] = f2b(b.z); o[7] = f2b(b.w);
    *(uint4*)(xb + i) = *(uint4*)o;
}

// K0: transpose+convert w_qkv fp32 [192,576] -> bf16 [576,192]
__global__ void k0_transpose(const float* __restrict__ w, ushort_t* __restrict__ bt) {
    int idx = blockIdx.x * 256 + threadIdx.x;        // 576*192 = 110592 exactly
    int n = idx / 192, k = idx - n * 192;
    bt[idx] = f2b(w[k * 576 + n]);
}

// MFMA GEMM: C[M,N] = A[M,192](bf16) * BT[N,192]^T(bf16) + bias(fp32).  64x64 tile,
// BK=64, 4 waves each 32x32 (2x2 of 16x16x32 bf16 mfma). bstride!=0 selects a
// per-batch B matrix by row/65536 (the fused attn*Wout matrix).
// n-tile on blockIdx.x, m-tile on blockIdx.y so consecutive blocks share A-tiles.
template <typename OutT>
__global__ __launch_bounds__(256) void gemm_k192(
    const ushort_t* __restrict__ A, int lda, int acol0,
    const ushort_t* __restrict__ BT, int bstride,
    const float* __restrict__ bias,
    OutT* __restrict__ Cout, int ldc)
{
    const int m0 = blockIdx.y * 64;
    const int n0 = blockIdx.x * 64;
    const ushort_t* bt = BT + (bstride ? (size_t)(m0 >> 16) * (size_t)bstride : 0);

    __shared__ ushort_t As[64 * 72];   // stride 72 elems: 16B-aligned rows
    __shared__ ushort_t Bs[64 * 72];

    const int t = threadIdx.x;
    const int wave = t >> 6, lane = t & 63;
    const int quad = lane >> 4, l15 = lane & 15;
    const int wm = (wave >> 1) * 32, wn = (wave & 1) * 32;
    const int srow = t >> 2, scol = (t & 3) * 16;

    f32x4 acc[2][2] = {};

    for (int kk = 0; kk < 192; kk += 64) {
        const ushort_t* ga = A + (size_t)(m0 + srow) * lda + acol0 + kk + scol;
        uint4 va0 = *(const uint4*)ga;
        uint4 va1 = *(const uint4*)(ga + 8);
        const ushort_t* gb = bt + (size_t)(n0 + srow) * 192 + kk + scol;
        uint4 vb0 = *(const uint4*)gb;
        uint4 vb1 = *(const uint4*)(gb + 8);
        *(uint4*)&As[srow * 72 + scol] = va0;
        *(uint4*)&As[srow * 72 + scol + 8] = va1;
        *(uint4*)&Bs[srow * 72 + scol] = vb0;
        *(uint4*)&Bs[srow * 72 + scol + 8] = vb1;
        __syncthreads();
#pragma unroll
        for (int ks = 0; ks < 2; ks++) {
            short8 a0 = *(const short8*)&As[(wm + l15) * 72 + ks * 32 + quad * 8];
            short8 a1 = *(const short8*)&As[(wm + 16 + l15) * 72 + ks * 32 + quad * 8];
            short8 b0 = *(const short8*)&Bs[(wn + l15) * 72 + ks * 32 + quad * 8];
            short8 b1 = *(const short8*)&Bs[(wn + 16 + l15) * 72 + ks * 32 + quad * 8];
            acc[0][0] = __builtin_amdgcn_mfma_f32_16x16x32_bf16(a0, b0, acc[0][0], 0, 0, 0);
            acc[0][1] = __builtin_amdgcn_mfma_f32_16x16x32_bf16(a0, b1, acc[0][1], 0, 0, 0);
            acc[1][0] = __builtin_amdgcn_mfma_f32_16x16x32_bf16(a1, b0, acc[1][0], 0, 0, 0);
            acc[1][1] = __builtin_amdgcn_mfma_f32_16x16x32_bf16(a1, b1, acc[1][1], 0, 0, 0);
        }
        __syncthreads();
    }
#pragma unroll
    for (int sm = 0; sm < 2; sm++) {
#pragma unroll
        for (int sn = 0; sn < 2; sn++) {
            int col = n0 + wn + sn * 16 + l15;
            float bv = bias ? bias[col] : 0.f;
#pragma unroll
            for (int r = 0; r < 4; r++) {
                int row = m0 + wm + sm * 16 + quad * 4 + r;
                storev(&Cout[(size_t)row * ldc + col], acc[sm][sn][r] + bv);
            }
        }
    }
}

// K2: 3x3 depthwise conv, SAME zero-pad, fp32 weights/bias, bf16 act in/out.
// Register-sliding: each thread owns (b, x, c8) and a strip of 16 output rows.
#define R_STRIP 16

__global__ __launch_bounds__(256) void k2_dwconv(const ushort_t* __restrict__ qkv0,
        const float* __restrict__ wdw, const float* __restrict__ bdw,
        ushort_t* __restrict__ qkv1)
{
    const int tid = blockIdx.x * 256 + threadIdx.x;   // 2*16*256*72 = 589,824 exactly
    const int c8 = tid % 72;
    const int t1 = tid / 72;                 // = (b*16 + s)*256 + x
    const int x  = t1 & 255;
    const int t2 = t1 >> 8;
    const int s  = t2 & 15;
    const int b  = t2 >> 4;
    const int y0 = s * R_STRIP;
    const int cbase = c8 * 8;

    const bool xm = (x > 0), xp = (x < 255);
    const ushort_t* colbase = qkv0 + ((size_t)(b * HW_ + x) * C3_ + cbase);
    ushort_t*       ocol    = qkv1 + ((size_t)(b * HW_ + x) * C3_ + cbase);
    const size_t rstride = (size_t)256 * C3_;         // elems per image row

    float w[3][3][8], bw[8];
#pragma unroll
    for (int ky = 0; ky < 3; ++ky)
#pragma unroll
        for (int kx = 0; kx < 3; ++kx) {
            const float* wp = wdw + ((ky * 3 + kx) * C3_ + cbase);
            float4 lo = *(const float4*)wp;
            float4 hi = *(const float4*)(wp + 4);
            w[ky][kx][0] = lo.x; w[ky][kx][1] = lo.y; w[ky][kx][2] = lo.z; w[ky][kx][3] = lo.w;
            w[ky][kx][4] = hi.x; w[ky][kx][5] = hi.y; w[ky][kx][6] = hi.z; w[ky][kx][7] = hi.w;
        }
    {
        float4 lo = *(const float4*)(bdw + cbase);
        float4 hi = *(const float4*)(bdw + cbase + 4);
        bw[0] = lo.x; bw[1] = lo.y; bw[2] = lo.z; bw[3] = lo.w;
        bw[4] = hi.x; bw[5] = hi.y; bw[6] = hi.z; bw[7] = hi.w;
    }

    const uint4 z4 = make_uint4(0, 0, 0, 0);
    auto loadrow = [&](int r, uint4& d0, uint4& d1, uint4& d2) {
        if ((unsigned)r <= 255u) {
            const ushort_t* p = colbase + (size_t)r * rstride;
            d1 = *(const uint4*)p;
            d0 = xm ? *(const uint4*)(p - C3_) : z4;
            d2 = xp ? *(const uint4*)(p + C3_) : z4;
        } else { d0 = z4; d1 = z4; d2 = z4; }
    };

    float A[3][8] = {};
    uint4 c0, c1, c2;
    loadrow(y0 - 1, c0, c1, c2);

#pragma unroll
    for (int RR = 0; RR < R_STRIP + 2; ++RR) {
        const int r = y0 - 1 + RR;
        uint4 n0 = z4, n1 = z4, n2 = z4;
        if (RR < R_STRIP + 1) loadrow(r + 1, n0, n1, n2);   // 1-step prefetch

        float rf[3][8];
        {
            const ushort_t* dd = (const ushort_t*)&c0;
#pragma unroll
            for (int j = 0; j < 8; ++j) rf[0][j] = b2f(dd[j]);
            dd = (const ushort_t*)&c1;
#pragma unroll
            for (int j = 0; j < 8; ++j) rf[1][j] = b2f(dd[j]);
            dd = (const ushort_t*)&c2;
#pragma unroll
            for (int j = 0; j < 8; ++j) rf[2][j] = b2f(dd[j]);
        }

        if (RR >= 1 && RR <= R_STRIP) {
#pragma unroll
            for (int kx = 0; kx < 3; ++kx)
#pragma unroll
                for (int j = 0; j < 8; ++j)
                    A[RR % 3][j] = fmaf(rf[kx][j], w[1][kx][j], A[RR % 3][j]);
        }
        if (RR <= R_STRIP - 1) {
#pragma unroll
            for (int kx = 0; kx < 3; ++kx)
#pragma unroll
                for (int j = 0; j < 8; ++j)
                    A[(RR + 1) % 3][j] = fmaf(rf[kx][j], w[0][kx][j], A[(RR + 1) % 3][j]);
        }
        if (RR >= 2) {
#pragma unroll
            for (int kx = 0; kx < 3; ++kx)
#pragma unroll
                for (int j = 0; j < 8; ++j)
                    A[(RR + 2) % 3][j] = fmaf(rf[kx][j], w[2][kx][j], A[(RR + 2) % 3][j]);
            ushort_t ov[8];
#pragma unroll
            for (int j = 0; j < 8; ++j) {
                ov[j] = f2b(A[(RR + 2) % 3][j] + bw[j]);
                A[(RR + 2) % 3][j] = 0.f;
            }
            *(uint4*)(ocol + (size_t)(r - 1) * rstride) = *(uint4*)ov;
        }
        c0 = n0; c1 = n1; c2 = n2;
    }
}

// K3 (MFMA): per (b,head) 96x96 Gram of Z=[Q|K] over a 1024-row slice.
// LDS stores the tile TRANSPOSED [z-ch][row] (stride 136 bf16) so MFMA A/B
// fragments are single ds_read_b128 (bank-group-balanced). 15 needed 16x16
// tiles: 9 S (QxK), 3 QQ-diag (->NQ), 3 KK-diag (->NK). Each wave covers one
// 32-row k-step per 128-row tile. Pairwise wave-reduce in LDS, then per-slice
// fp32 partials to P (aliases dead qkv0); k3r_reduce sums 128 partials.
#define GR_LDSSTRIDE 136

__global__ __launch_bounds__(256) void k3_gram_mfma(const ushort_t* __restrict__ qkv1,
        float* __restrict__ P)
{
    const int bh = blockIdx.y;              // 0..7
    const int b = bh >> 2, h = bh & 3;
    const int slice = blockIdx.x;           // 0..63
    const int t = threadIdx.x;
    const int wave = t >> 6, lane = t & 63;
    const int quad = lane >> 4, l15 = lane & 15;

    __shared__ float red[7680];             // 30,720 B; low 26,112 B doubles as bf16 stage
    ushort_t* Z = (ushort_t*)red;

    f32x4 acc[15] = {};
    const ushort_t* basep = qkv1 + (size_t)(b * HW_) * C3_;
    const int row = t & 127;
    const int seghalf = t >> 7;             // 0: even segs, 1: odd segs

    for (int tile = 0; tile < 8; ++tile) {
        const int nbase = slice * 1024 + tile * 128;
        uint4 u[6];
#pragma unroll
        for (int k = 0; k < 6; ++k) {       // issue loads before barrier: overlap prev compute
            int seg = k * 2 + seghalf;      // 0..11; segs 0-5 = Q chans, 6-11 = K chans
            int cg = (seg < 6) ? (h * CH_ + seg * 8) : (C_ + h * CH_ + (seg - 6) * 8);
            u[k] = *(const uint4*)(basep + (size_t)(nbase + row) * C3_ + cg);
        }
        __syncthreads();                    // previous tile's compute done
#pragma unroll
        for (int k = 0; k < 6; ++k) {
            int seg = k * 2 + seghalf;
            int zc = seg * 8;               // z-channel base (Q:0-47, K:48-95)
            const ushort_t* dd = (const ushort_t*)&u[k];
#pragma unroll
            for (int j = 0; j < 8; ++j)
                Z[(zc + j) * GR_LDSSTRIDE + row] = dd[j];
        }
        __syncthreads();
        const int n0 = wave * 32 + quad * 8;
        short8 F[6];
#pragma unroll
        for (int c = 0; c < 6; ++c)
            F[c] = *(const short8*)&Z[(c * 16 + l15) * GR_LDSSTRIDE + n0];
#pragma unroll
        for (int i = 0; i < 3; ++i)
#pragma unroll
            for (int j = 0; j < 3; ++j)
                acc[i * 3 + j] = __builtin_amdgcn_mfma_f32_16x16x32_bf16(F[i], F[3 + j], acc[i * 3 + j], 0, 0, 0);
#pragma unroll
        for (int i = 0; i < 3; ++i) {
            acc[9 + i]  = __builtin_amdgcn_mfma_f32_16x16x32_bf16(F[i], F[i], acc[9 + i], 0, 0, 0);
            acc[12 + i] = __builtin_amdgcn_mfma_f32_16x16x32_bf16(F[3 + i], F[3 + i], acc[12 + i], 0, 0, 0);
        }
    }

    // pairwise cross-wave reduce: waves 1,3 -> LDS; waves 0,2 add and store
    __syncthreads();
    if (wave & 1) {
        float* dst = red + (wave >> 1) * (15 * 256);
#pragma unroll
        for (int tt = 0; tt < 15; ++tt)
            *(f32x4*)&dst[tt * 256 + lane * 4] = acc[tt];
    }
    __syncthreads();
    if (!(wave & 1)) {
        const float* src = red + (wave >> 1) * (15 * 256);
        const int sp = slice * 2 + (wave >> 1);     // 0..127
#pragma unroll
        for (int tt = 0; tt < 15; ++tt) {
            f32x4 v = *(const f32x4*)&src[tt * 256 + lane * 4];
#pragma unroll
            for (int r = 0; r < 4; ++r) {
                int e = (quad * 4 + r) * 16 + l15;  // row*16+col of the 16x16 tile
                P[(((size_t)bh * 15 + tt) * 128 + sp) * 256 + e] = acc[tt][r] + v[r];
            }
        }
    }
}

// K3r: sum the 128 per-slice partials; emit S (9 off-diag tiles), NQ/NK (diag tiles)
__global__ __launch_bounds__(256) void k3r_reduce(const float* __restrict__ P,
        float* __restrict__ S, float* __restrict__ NQ, float* __restrict__ NK)
{
    int idx = blockIdx.x * 256 + threadIdx.x;   // 8*15*256 = 30,720 exactly (120 blocks)
    int bh = idx / 3840;
    int rem = idx - bh * 3840;
    int tt = rem >> 8;
    int e = rem & 255;
    const float* p = P + (((size_t)bh * 15 + tt) * 128) * 256 + e;
    float s = 0.f;
#pragma unroll 8
    for (int sp = 0; sp < 128; ++sp) s += p[(size_t)sp * 256];
    int r = e >> 4, c = e & 15;
    if (tt < 9) {
        int i = tt / 3, j = tt - i * 3;
        S[bh * 2304 + (i * 16 + r) * 48 + j * 16 + c] = s;
    } else if (tt < 12) {
        if (r == c) NQ[bh * 48 + (tt - 9) * 16 + r] = s;
    } else {
        if (r == c) NK[bh * 48 + (tt - 12) * 16 + r] = s;
    }
}

// K4a: attn = softmax_row( S * temp / (|q||k|) ), one 64-thread block per (bh,cq) row
__global__ void k4a_softmax(const float* __restrict__ S, const float* __restrict__ NQ,
                            const float* __restrict__ NK, const float* __restrict__ temp,
                            float* __restrict__ ATT)
{
    int bh = blockIdx.y, cq = blockIdx.x;
    int h = bh & 3;
    int t = threadIdx.x;
    float nq = fmaxf(sqrtf(NQ[bh * 48 + cq]), 1e-12f);
    float tv = temp[h];
    float logit = -1e30f;
    if (t < 48) {
        float nk = fmaxf(sqrtf(NK[bh * 48 + t]), 1e-12f);
        logit = S[bh * 2304 + cq * 48 + t] * tv / (nq * nk);
    }
    float m = logit;
    for (int o = 32; o > 0; o >>= 1) m = fmaxf(m, __shfl_xor(m, o));
    float e = (t < 48) ? __expf(logit - m) : 0.f;
    float ssum = e;
    for (int o = 32; o > 0; o >>= 1) ssum += __shfl_xor(ssum, o);
    if (t < 48) ATT[bh * 2304 + cq * 48 + t] = e / ssum;
}

// K4b: fuse attention-apply + output projection into one per-batch 192x192 matrix,
// stored TRANSPOSED so the final GEMM's B-operand reads contiguous K.
__global__ void k4b_buildM(const float* __restrict__ ATT, const float* __restrict__ wout,
                           ushort_t* __restrict__ MT)
{
    int idx = blockIdx.x * 256 + threadIdx.x;      // 2*192*192 = 73728 exactly
    int b = idx / 36864; int rem = idx - b * 36864;
    int j = rem / 192;   int d = rem - j * 192;
    int h = d / 48, dd = d - h * 48;
    const float* ap = ATT + (size_t)(b * 4 + h) * 2304 + dd;   // stride 48 over cq
    const float* wp = wout + (size_t)(h * 48) * 192 + j;       // stride 192 over cq
    float s = 0.f;
#pragma unroll 8
    for (int cq = 0; cq < 48; cq++) s += ap[cq * 48] * wp[cq * 192];
    MT[idx] = f2b(s);
}

extern "C" void kernel_launch(void* const* d_in, const int* in_sizes, int n_in,
                              void* d_out, int out_size, void* d_ws, size_t ws_size,
                              hipStream_t stream) {
    const float* x     = (const float*)d_in[0];
    const float* w_qkv = (const float*)d_in[1];
    const float* b_qkv = (const float*)d_in[2];
    const float* w_dw  = (const float*)d_in[3];
    const float* b_dw  = (const float*)d_in[4];
    const float* temp  = (const float*)d_in[5];
    const float* w_out = (const float*)d_in[6];
    const float* b_out = (const float*)d_in[7];
    float* out = (float*)d_out;

    char* ws = (char*)d_ws;
    ushort_t* qkv0 = (ushort_t*)(ws + OFF_QKV0);
    ushort_t* qkv1 = (ushort_t*)(ws + OFF_QKV1);
    ushort_t* xb   = (ushort_t*)(ws + OFF_XB);
    float*    Pb   = (float*)(ws + OFF_P);
    ushort_t* btq  = (ushort_t*)(ws + OFF_BT);
    float*    Sb   = (float*)(ws + OFF_S);
    float*    NQ   = (float*)(ws + OFF_NQ);
    float*    NK   = (float*)(ws + OFF_NK);
    float*    ATT  = (float*)(ws + OFF_ATTN);
    ushort_t* MT   = (ushort_t*)(ws + OFF_MT);

    k_cvt_x<<<12288, 256, 0, stream>>>(x, xb);
    k0_transpose<<<432, 256, 0, stream>>>(w_qkv, btq);
    // qkv0 = x @ w_qkv + b_qkv   (bf16 out)
    gemm_k192<ushort_t><<<dim3(9, 2048), 256, 0, stream>>>(xb, 192, 0, btq, 0, b_qkv, qkv0, 576);
    // qkv1 = depthwise3x3(qkv0) + b_dw   (clobbers xb — xb is dead here)
    k2_dwconv<<<2304, 256, 0, stream>>>(qkv0, w_dw, b_dw, qkv1);
    // MFMA Gram partials (P aliases dead qkv0), then reduce -> S, NQ, NK
    k3_gram_mfma<<<dim3(64, 8), 256, 0, stream>>>(qkv1, Pb);
    k3r_reduce<<<120, 256, 0, stream>>>(Pb, Sb, NQ, NK);
    // softmax(normalized, temperature-scaled)
    k4a_softmax<<<dim3(48, 8), 64, 0, stream>>>(Sb, NQ, NK, temp, ATT);
    // fused (blockdiag attn)^T @ Wout, transposed for the GEMM
    k4b_buildM<<<288, 256, 0, stream>>>(ATT, w_out, MT);
    // out = v @ M_b + b_out   (fp32 out)
    gemm_k192<float><<<dim3(3, 2048), 256, 0, stream>>>(qkv1, 576, 384, MT, 36864, b_out, out, 192);
}